// Round 2
// baseline (196.456 us; speedup 1.0000x reference)
//
#include <hip/hip_runtime.h>
#include <hip/hip_cooperative_groups.h>
#include <hip/hip_fp16.h>
#include <math.h>

namespace cg = cooperative_groups;

#define BATCH 8
#define NSLOT 256
#define DDIM  256
#define HID   128
#define NREL  8

typedef _Float16 half8 __attribute__((ext_vector_type(8)));
typedef float float4v __attribute__((ext_vector_type(4)));

union U8 {
  uint32_t u[4];
  _Float16 f[8];
  half8 v;
  float4 f4;
};

// ---------------------------------------------------------------------------
// R15: 2 kernels -> 1 cooperative kernel. R14 showed each serial dispatch
// boundary costs ~5us (wt removal: 85.2 -> 79.65 while wt itself models ~2us).
// Phase 1 == R14 proj_kernel body (2048 wave-tasks over 4096 waves);
// grid.sync(); Phase 2 == R14 pair_kernel body (validated session-best
// structure). 1024 blocks x 256 thr = 4 blocks/CU co-resident
// (launch_bounds(256,4) caps VGPR at 128 to guarantee cooperative fit).
// d_ws layout: P f16[2048][256] at offset 0 (1 MB).
//
// MFMA maps (HW-validated in prior session R5-R12):
//   A[m=lane&15][k=(lane>>4)*8+u], B[k=(lane>>4)*8+u][n=lane&15],
//   D[m=(lane>>4)*4+reg][n=lane&15].
// ---------------------------------------------------------------------------
__global__ __launch_bounds__(256, 4) void fused_kernel(
    const float* __restrict__ slots, const float* __restrict__ W1,
    const float* __restrict__ b1, const float* __restrict__ W2,
    const float* __restrict__ b2, float* __restrict__ out,
    _Float16* __restrict__ P) {
  __shared__ uint32_t PiL[8 * 68];

  const int tid  = threadIdx.x;
  const int w    = tid >> 6;
  const int lane = tid & 63;
  const int lo16 = lane & 15;
  const int kg   = lane >> 4;

  // ---------------- Phase 1: proj (exactly R14 proj_kernel) ----------------
  // P[r][c] = dot(slots[r], concatW[:,c]) + (c<128 ? b1[c] : 0)
  // wave-task t in [0,2048): c-tile = t & 15, row-block = t >> 4.
  {
    const int t = blockIdx.x * 4 + w;
    if (t < 2048) {
      const int ct   = t & 15;
      const int rb   = t >> 4;
      const int row0 = rb * 16;
      const int c    = ct * 16 + lo16;

      const float* Wcol =
          (c < HID) ? (W1 + c) : (W1 + (size_t)DDIM * HID + (c - HID));
      U8 bf[8];
#pragma unroll
      for (int ks = 0; ks < 8; ++ks) {
        const int kb = ks * 32 + kg * 8;
#pragma unroll
        for (int u = 0; u < 8; ++u)
          bf[ks].f[u] = (_Float16)Wcol[(size_t)(kb + u) * HID];
      }

      float4v acc = {0.0f, 0.0f, 0.0f, 0.0f};
      const float* srow = slots + (size_t)(row0 + lo16) * DDIM;
#pragma unroll
      for (int ks = 0; ks < 8; ++ks) {
        const float4 x0 = *(const float4*)(srow + ks * 32 + kg * 8);
        const float4 x1 = *(const float4*)(srow + ks * 32 + kg * 8 + 4);
        U8 a;
        a.f[0] = (_Float16)x0.x; a.f[1] = (_Float16)x0.y;
        a.f[2] = (_Float16)x0.z; a.f[3] = (_Float16)x0.w;
        a.f[4] = (_Float16)x1.x; a.f[5] = (_Float16)x1.y;
        a.f[6] = (_Float16)x1.z; a.f[7] = (_Float16)x1.w;
        acc =
            __builtin_amdgcn_mfma_f32_16x16x32_f16(a.v, bf[ks].v, acc, 0, 0, 0);
      }

      const float bias = (c < HID) ? b1[c] : 0.0f;
#pragma unroll
      for (int reg = 0; reg < 4; ++reg)
        P[(size_t)(row0 + kg * 4 + reg) * 256 + c] = (_Float16)(acc[reg] + bias);
    }
  }

  cg::this_grid().sync();

  // ---------------- Phase 2: pair (exactly R14 pair_kernel) ----------------
  // out[b,i,j,r] = sigmoid( sum_k relu(P[b,i,k]+P[b,j,128+k]) * W2[k,r] + b2[r] )
  {
    const int bx = blockIdx.x;
    const int b  = bx >> 7;
    const int i0 = ((bx >> 2) & 31) * 8;
    const int j0 = (bx & 3) * 64 + w * 16;
    const int n  = lo16;
    const _Float16* Pb = P + (size_t)b * NSLOT * 256;

    if (tid < 128) {  // stage Pi: 8 rows x 128 f16
      const int r  = tid >> 4;
      const int ch = tid & 15;
      const float4 t = *(const float4*)(Pb + (size_t)(i0 + r) * 256 + ch * 8);
      *(float4*)&PiL[r * 68 + ch * 4] = t;
    }

    // W2 B-frag direct: w2f[kq].f[u] = (n<8) ? (f16)W2[(kq*32+kg*8+u)*8+n] : 0
    U8 w2f[4];
#pragma unroll
    for (int kq = 0; kq < 4; ++kq) {
      const int kb = kq * 32 + kg * 8;
#pragma unroll
      for (int u = 0; u < 8; ++u) {
        const float v = W2[(kb + u) * NREL + (n & 7)];  // 4KB, L1-resident
        w2f[kq].f[u] = (n < NREL) ? (_Float16)v : (_Float16)0.0f;
      }
    }

    const float b2v = (n < NREL) ? b2[n & 7] : 0.0f;

    U8 pj[4];
#pragma unroll
    for (int kq = 0; kq < 4; ++kq)
      pj[kq].f4 = *(const float4*)(Pb + (size_t)(j0 + n) * 256 + HID +
                                   kq * 32 + kg * 8);

    __syncthreads();

#pragma unroll
    for (int i = 0; i < 8; ++i) {
      float4v acc = {0.0f, 0.0f, 0.0f, 0.0f};
#pragma unroll
      for (int kq = 0; kq < 4; ++kq) {
        U8 pi;
        pi.f4 = *(const float4*)&PiL[i * 68 + kq * 16 + kg * 4];  // broadcast
        U8 h;
        h.v = __builtin_elementwise_max(pj[kq].v + pi.v, (half8)(_Float16)0.0f);
        acc =
            __builtin_amdgcn_mfma_f32_16x16x32_f16(h.v, w2f[kq].v, acc, 0, 0, 0);
      }
      if (n < NREL) {
        float* obase =
            out + (((size_t)b * NSLOT + (i0 + i)) * NSLOT + j0) * NREL + n;
#pragma unroll
        for (int reg = 0; reg < 4; ++reg) {
          const int jrow = kg * 4 + reg;
          const float x = acc[reg] + b2v;
          obase[jrow * NREL] = __builtin_amdgcn_rcpf(1.0f + __expf(-x));
        }
      }
    }
  }
}

extern "C" void kernel_launch(void* const* d_in, const int* in_sizes, int n_in,
                              void* d_out, int out_size, void* d_ws,
                              size_t ws_size, hipStream_t stream) {
  const float* slots = (const float*)d_in[0];  // [8,256,256]
  const float* W1    = (const float*)d_in[1];  // [512,128]
  const float* b1    = (const float*)d_in[2];  // [128]
  const float* W2    = (const float*)d_in[3];  // [128,8]
  const float* b2    = (const float*)d_in[4];  // [8]
  float* out  = (float*)d_out;                 // [8,256,256,8]
  _Float16* P = (_Float16*)d_ws;               // 1 MB

  void* args[] = {(void*)&slots, (void*)&W1, (void*)&b1, (void*)&W2,
                  (void*)&b2,    (void*)&out, (void*)&P};
  hipLaunchCooperativeKernel((const void*)fused_kernel, dim3(1024), dim3(256),
                             args, 0, stream);
}

// Round 3
// 87.358 us; speedup vs baseline: 2.2489x; 2.2489x over previous
//
#include <hip/hip_runtime.h>
#include <hip/hip_fp16.h>
#include <math.h>

#define BATCH 8
#define NSLOT 256
#define DDIM  256
#define HID   128
#define NREL  8

typedef _Float16 half8 __attribute__((ext_vector_type(8)));
typedef float float4v __attribute__((ext_vector_type(4)));

union U8 {
  uint32_t u[4];
  _Float16 f[8];
  half8 v;
  float4 f4;
};

union U4 {
  uint32_t u[2];
  _Float16 f[4];
  uint2 u2;
};

// ---------------------------------------------------------------------------
// R16: single CONVENTIONAL kernel (no grid.sync — R15 showed cooperative
// grid.sync costs ~100us on this stack; no d_ws — P never materialized).
// Grid 256 blocks (32 i-groups x 8 batches) x 512 thr = 1 block/CU, 130KB LDS.
// Per block: stage W1-upper f16 -> LDS (XOR-swizzled, G4/T2 shape), compute
// Pi (8 rows x 128 + b1) -> LDS, ONE barrier, then each wave independently:
// Pj^T for its 2 j-tiles via mfma(Wu, slots^T) -> wave-private slab, then the
// R14-validated pair body (relu-add, W2 mfma, sigmoid, identical out stores).
// Recompute cost: proj is 0.27 GFLOP total -> trivial on matrix pipe.
//
// MFMA maps (HW-validated R5-R12 prior session):
//   A[m=lane&15][k=(lane>>4)*8+u], B[k=(lane>>4)*8+u][n=lane&15],
//   D[m=(lane>>4)*4+reg][n=lane&15].
// Pj^T trick: A=Wu (m=c), B=slots^T (n=j) => D[m=c][n=j] = proj_j[j][c];
// lane's 4 D-regs = 4 CONSECUTIVE c of one j-row -> single b64 slab store.
// ---------------------------------------------------------------------------

// XOR swizzle on bits 4..6 of the within-row byte offset, keyed by row (G4:
// byte ^= ((row&7)<<4)). Applied identically on write and read -> bijective.
__device__ __forceinline__ int swz(int row, int off) {
  return (off & ~0x70) | ((((off >> 4) ^ row) & 7) << 4);
}

__global__ __launch_bounds__(512, 2) void fused_kernel(
    const float* __restrict__ slots, const float* __restrict__ W1,
    const float* __restrict__ b1, const float* __restrict__ W2,
    const float* __restrict__ b2, float* __restrict__ out) {
  // LDS: Wu 64KB (swizzled [c][k], c=0..127 rows of 256 f16),
  //      Slab 64KB (8 waves x 2 jt x [16 j][128 c] f16, swizzled),
  //      Pi 2KB ([8 i][128 c] f16, linear: reads are broadcast).
  __shared__ _Float16 WuS[128 * 256];
  __shared__ _Float16 SlabS[8][2][16 * 128];
  __shared__ _Float16 PiS[8 * 128];

  const int tid  = threadIdx.x;
  const int w    = tid >> 6;
  const int lane = tid & 63;
  const int lo16 = lane & 15;
  const int kg   = lane >> 4;

  const int b  = blockIdx.y;
  const int i0 = blockIdx.x * 8;
  const float* sb = slots + (size_t)b * NSLOT * DDIM;

  // ---- Phase 0: stage W1-upper (rows 256..511) as f16 into Wu[c][k] ----
  // Wu[c][k] = (f16) W1[256+k][c].  Thread: c = tid&127, k-blocks strided.
  {
    const int c = tid & 127;
    const int kb0 = tid >> 7;  // 0..3
    const float* Wup = W1 + (size_t)DDIM * HID;  // row 256
#pragma unroll
    for (int s = 0; s < 8; ++s) {
      const int kb = kb0 + s * 4;  // 0..31
      U8 p;
#pragma unroll
      for (int u = 0; u < 8; ++u)
        p.f[u] = (_Float16)Wup[(size_t)(kb * 8 + u) * HID + c];
      *(float4*)((char*)WuS + c * 512 + swz(c, kb * 16)) = p.f4;
    }
  }

  // ---- Phase 1: Pi strip per wave (c = w*16+lo16), R14 proj pattern ----
  {
    const int c = w * 16 + lo16;          // 0..127
    const float* Wcol = W1 + c;           // lower half rows 0..255
    U8 bf[8];
#pragma unroll
    for (int ks = 0; ks < 8; ++ks) {
      const int kb = ks * 32 + kg * 8;
#pragma unroll
      for (int u = 0; u < 8; ++u)
        bf[ks].f[u] = (_Float16)Wcol[(size_t)(kb + u) * HID];
    }
    int arow = i0 + lo16;
    if (arow > NSLOT - 1) arow = NSLOT - 1;  // rows >= i0+8 are discarded
    const float* srow = sb + (size_t)arow * DDIM;
    float4v acc = {0.0f, 0.0f, 0.0f, 0.0f};
#pragma unroll
    for (int ks = 0; ks < 8; ++ks) {
      const float4 x0 = *(const float4*)(srow + ks * 32 + kg * 8);
      const float4 x1 = *(const float4*)(srow + ks * 32 + kg * 8 + 4);
      U8 a;
      a.f[0] = (_Float16)x0.x; a.f[1] = (_Float16)x0.y;
      a.f[2] = (_Float16)x0.z; a.f[3] = (_Float16)x0.w;
      a.f[4] = (_Float16)x1.x; a.f[5] = (_Float16)x1.y;
      a.f[6] = (_Float16)x1.z; a.f[7] = (_Float16)x1.w;
      acc = __builtin_amdgcn_mfma_f32_16x16x32_f16(a.v, bf[ks].v, acc, 0, 0, 0);
    }
    const float bias = b1[c];
#pragma unroll
    for (int reg = 0; reg < 4; ++reg) {
      const int m = kg * 4 + reg;
      if (m < 8) PiS[m * 128 + c] = (_Float16)(acc[reg] + bias);
    }
  }

  // ---- Preload (no LDS dependency -> before barrier): Bs, W2 frags, b2 ----
  // Bs[t][ks] = slots^T B-frag for j-tile t: B[k][n=j] = slots[j0t+lo16][k].
  U8 Bs[2][8];
#pragma unroll
  for (int t = 0; t < 2; ++t) {
    const int j0t = (2 * w + t) * 16;
    const float* srow = sb + (size_t)(j0t + lo16) * DDIM;
#pragma unroll
    for (int ks = 0; ks < 8; ++ks) {
      const float4 x0 = *(const float4*)(srow + ks * 32 + kg * 8);
      const float4 x1 = *(const float4*)(srow + ks * 32 + kg * 8 + 4);
      Bs[t][ks].f[0] = (_Float16)x0.x; Bs[t][ks].f[1] = (_Float16)x0.y;
      Bs[t][ks].f[2] = (_Float16)x0.z; Bs[t][ks].f[3] = (_Float16)x0.w;
      Bs[t][ks].f[4] = (_Float16)x1.x; Bs[t][ks].f[5] = (_Float16)x1.y;
      Bs[t][ks].f[6] = (_Float16)x1.z; Bs[t][ks].f[7] = (_Float16)x1.w;
    }
  }
  U8 w2f[4];
#pragma unroll
  for (int kq = 0; kq < 4; ++kq) {
    const int kb = kq * 32 + kg * 8;
#pragma unroll
    for (int u = 0; u < 8; ++u) {
      const float v = W2[(kb + u) * NREL + (lo16 & 7)];  // 4KB, L1-resident
      w2f[kq].f[u] = (lo16 < NREL) ? (_Float16)v : (_Float16)0.0f;
    }
  }
  const float b2v = (lo16 < NREL) ? b2[lo16 & 7] : 0.0f;

  __syncthreads();  // the ONLY barrier: Wu + Pi visible to all waves

  // ---- Phase 2: Pj^T into wave-private slab (2 j-tiles per wave) ----
  _Float16* myslab0 = &SlabS[w][0][0];
  _Float16* myslab1 = &SlabS[w][1][0];
#pragma unroll
  for (int ct = 0; ct < 8; ++ct) {
    const int c = ct * 16 + lo16;  // A row m = c
    U8 af[8];
#pragma unroll
    for (int ks = 0; ks < 8; ++ks)
      af[ks].f4 = *(const float4*)((const char*)WuS + c * 512 +
                                   swz(c, ks * 64 + kg * 16));
    float4v d0 = {0.0f, 0.0f, 0.0f, 0.0f};
    float4v d1 = {0.0f, 0.0f, 0.0f, 0.0f};
#pragma unroll
    for (int ks = 0; ks < 8; ++ks) {
      d0 = __builtin_amdgcn_mfma_f32_16x16x32_f16(af[ks].v, Bs[0][ks].v, d0, 0, 0, 0);
      d1 = __builtin_amdgcn_mfma_f32_16x16x32_f16(af[ks].v, Bs[1][ks].v, d1, 0, 0, 0);
    }
    // D: lane holds proj_j[j = j0t+lo16][c = ct*16+kg*4+reg], reg=0..3
    // -> 4 consecutive c: pack and b64-store into slab row lo16.
    U4 s0, s1;
#pragma unroll
    for (int r4 = 0; r4 < 4; ++r4) {
      s0.f[r4] = (_Float16)d0[r4];
      s1.f[r4] = (_Float16)d1[r4];
    }
    const int off = ct * 32 + kg * 8;
    *(uint2*)((char*)myslab0 + lo16 * 256 + swz(lo16, off)) = s0.u2;
    *(uint2*)((char*)myslab1 + lo16 * 256 + swz(lo16, off)) = s1.u2;
  }

  // ---- Phase 3: pair (R14-validated body; pj from slab, pi from PiS) ----
  U8 pjf[2][4];
#pragma unroll
  for (int t = 0; t < 2; ++t) {
    const char* base = (const char*)(t ? myslab1 : myslab0);
#pragma unroll
    for (int kq = 0; kq < 4; ++kq)
      pjf[t][kq].f4 = *(const float4*)(base + lo16 * 256 +
                                       swz(lo16, kq * 64 + kg * 16));
  }

#pragma unroll
  for (int i = 0; i < 8; ++i) {
    U8 pif[4];
#pragma unroll
    for (int kq = 0; kq < 4; ++kq)  // broadcast reads, conflict-free
      pif[kq].f4 = *(const float4*)&PiS[i * 128 + kq * 32 + kg * 8];
#pragma unroll
    for (int t = 0; t < 2; ++t) {
      const int j0t = (2 * w + t) * 16;
      float4v acc = {0.0f, 0.0f, 0.0f, 0.0f};
#pragma unroll
      for (int kq = 0; kq < 4; ++kq) {
        U8 h;
        h.v = __builtin_elementwise_max(pjf[t][kq].v + pif[kq].v,
                                        (half8)(_Float16)0.0f);
        acc = __builtin_amdgcn_mfma_f32_16x16x32_f16(h.v, w2f[kq].v, acc, 0, 0, 0);
      }
      if (lo16 < NREL) {
        float* obase =
            out + (((size_t)b * NSLOT + (i0 + i)) * NSLOT + j0t) * NREL + lo16;
#pragma unroll
        for (int reg = 0; reg < 4; ++reg) {
          const int jrow = kg * 4 + reg;
          const float x = acc[reg] + b2v;
          obase[jrow * NREL] = __builtin_amdgcn_rcpf(1.0f + __expf(-x));
        }
      }
    }
  }
}

extern "C" void kernel_launch(void* const* d_in, const int* in_sizes, int n_in,
                              void* d_out, int out_size, void* d_ws,
                              size_t ws_size, hipStream_t stream) {
  const float* slots = (const float*)d_in[0];  // [8,256,256]
  const float* W1    = (const float*)d_in[1];  // [512,128]
  const float* b1    = (const float*)d_in[2];  // [128]
  const float* W2    = (const float*)d_in[3];  // [128,8]
  const float* b2    = (const float*)d_in[4];  // [8]
  float* out = (float*)d_out;                  // [8,256,256,8]
  (void)d_ws; (void)ws_size;                   // workspace unused: P is never materialized

  fused_kernel<<<dim3(NSLOT / 8, BATCH), 512, 0, stream>>>(slots, W1, b1, W2,
                                                           b2, out);
}